// Round 1
// baseline (608.215 us; speedup 1.0000x reference)
//
#include <hip/hip_runtime.h>
#include <hip/hip_bf16.h>
#include <math.h>

#define MM 256
#define LL 4096
#define TT 2048

// ---------------- reductions ----------------
__device__ __forceinline__ float wave_red_sum(float v) {
#pragma unroll
  for (int o = 32; o > 0; o >>= 1) v += __shfl_down(v, o);
  return v;
}
__device__ __forceinline__ float wave_red_max(float v) {
#pragma unroll
  for (int o = 32; o > 0; o >>= 1) v = fmaxf(v, __shfl_down(v, o));
  return v;
}
__device__ float blk_red_sum(float v) {  // blockDim.x == 256
  __shared__ float sh[4];
  int lane = threadIdx.x & 63, wv = threadIdx.x >> 6;
  v = wave_red_sum(v);
  __syncthreads();
  if (lane == 0) sh[wv] = v;
  __syncthreads();
  return sh[0] + sh[1] + sh[2] + sh[3];
}
__device__ float blk_red_max(float v) {
  __shared__ float shm[4];
  int lane = threadIdx.x & 63, wv = threadIdx.x >> 6;
  v = wave_red_max(v);
  __syncthreads();
  if (lane == 0) shm[wv] = v;
  __syncthreads();
  return fmaxf(fmaxf(shm[0], shm[1]), fmaxf(shm[2], shm[3]));
}

// ---------------- init: R = ridge*I, G = 0 ----------------
__global__ __launch_bounds__(256) void k_init(float2* __restrict__ R, float2* __restrict__ G) {
  int idx = blockIdx.x * 256 + threadIdx.x;  // 65536
  float re = ((idx % 257) == 0) ? 0.01f : 0.0f;
  R[idx] = make_float2(re, 0.0f);
  G[idx] = make_float2(0.0f, 0.0f);
}

// ---------------- pack A planes to float2 ----------------
__global__ __launch_bounds__(256) void k_pack(const float* __restrict__ Are,
                                              const float* __restrict__ Aim,
                                              float2* __restrict__ Apk) {
  int idx = blockIdx.x * 256 + threadIdx.x;  // MM*LL
  Apk[idx] = make_float2(Are[idx], Aim[idx]);
}

// ---------------- Gram: C[i,j] += sum_k alpha[k]*U[i,k]*conj(U[j,k]) ----------------
// grid: (16 tiles of 64x64, 16 K-splits); atomicAdd accumulate.
__global__ __launch_bounds__(256) void k_gram(const float* __restrict__ Ure,
                                              const float* __restrict__ Uim,
                                              const float* __restrict__ alpha,
                                              int K, int Kc, float2* __restrict__ C) {
  __shared__ float Ur[16][67], Ui[16][67], Vr[16][67], Vi[16][67];
  int tile = blockIdx.x;
  int i0 = (tile >> 2) * 64, j0 = (tile & 3) * 64;
  int k0 = blockIdx.y * Kc;
  int tid = threadIdx.x;
  int tx = tid & 15, ty = tid >> 4;
  float accR[4][4] = {}, accI[4][4] = {};
  int col = tid & 15, rowb = tid >> 4;
  for (int kb = 0; kb < Kc; kb += 16) {
    int kg = k0 + kb + col;
    float a = alpha ? alpha[kg] : 1.0f;
    __syncthreads();
#pragma unroll
    for (int r = 0; r < 4; ++r) {
      int row = rowb + 16 * r;
      float ur = Ure[(size_t)(i0 + row) * K + kg];
      float ui = Uim[(size_t)(i0 + row) * K + kg];
      Ur[col][row] = ur * a;
      Ui[col][row] = ui * a;
      Vr[col][row] = Ure[(size_t)(j0 + row) * K + kg];
      Vi[col][row] = Uim[(size_t)(j0 + row) * K + kg];
    }
    __syncthreads();
#pragma unroll
    for (int kk = 0; kk < 16; ++kk) {
      float ar[4], ai[4], br[4], bi[4];
#pragma unroll
      for (int r = 0; r < 4; ++r) { ar[r] = Ur[kk][ty + 16 * r]; ai[r] = Ui[kk][ty + 16 * r]; }
#pragma unroll
      for (int c = 0; c < 4; ++c) { br[c] = Vr[kk][tx + 16 * c]; bi[c] = Vi[kk][tx + 16 * c]; }
#pragma unroll
      for (int r = 0; r < 4; ++r)
#pragma unroll
        for (int c = 0; c < 4; ++c) {
          accR[r][c] += ar[r] * br[c] + ai[r] * bi[c];
          accI[r][c] += ai[r] * br[c] - ar[r] * bi[c];
        }
    }
  }
#pragma unroll
  for (int r = 0; r < 4; ++r)
#pragma unroll
    for (int c = 0; c < 4; ++c) {
      float* p = &C[(i0 + ty + 16 * r) * MM + (j0 + tx + 16 * c)].x;
      atomicAdd(p, accR[r][c]);
      atomicAdd(p + 1, accI[r][c]);
    }
}

// ---------------- Newton X0 = diag(R)^-1 ----------------
__global__ __launch_bounds__(256) void k_x0(const float2* __restrict__ R, float2* __restrict__ X) {
  int idx = blockIdx.x * 256 + threadIdx.x;
  int i = idx >> 8, j = idx & 255;
  float v = (i == j) ? (1.0f / R[i * 257].x) : 0.0f;
  X[idx] = make_float2(v, 0.0f);
}

// ---------------- 256x256x256 complex matmul; mode1: C = 2A - A@B ----------------
__global__ __launch_bounds__(256) void k_zgemm256(const float2* __restrict__ A,
                                                  const float2* __restrict__ B,
                                                  float2* __restrict__ C, int mode) {
  __shared__ float2 As[16][17], Bs[16][17];
  int bi = blockIdx.x >> 4, bj = blockIdx.x & 15;
  int i0 = bi * 16, j0 = bj * 16;
  int tx = threadIdx.x & 15, ty = threadIdx.x >> 4;
  float accx = 0.f, accy = 0.f;
  for (int k0 = 0; k0 < 256; k0 += 16) {
    __syncthreads();
    As[ty][tx] = A[(i0 + ty) * 256 + k0 + tx];
    Bs[ty][tx] = B[(k0 + ty) * 256 + j0 + tx];
    __syncthreads();
#pragma unroll
    for (int kk = 0; kk < 16; ++kk) {
      float2 a = As[ty][kk], b = Bs[kk][tx];
      accx += a.x * b.x - a.y * b.y;
      accy += a.x * b.y + a.y * b.x;
    }
  }
  int idx = (i0 + ty) * 256 + j0 + tx;
  if (mode) {
    float2 x = A[idx];
    accx = 2.0f * x.x - accx;
    accy = 2.0f * x.y - accy;
  }
  C[idx] = make_float2(accx, accy);
}

// ---------------- wide complex matmul: C[256 x 4096] = A[256x256] @ B[256x4096] ----------------
// tile 32(i) x 64(j); grid (64, 8)
__global__ __launch_bounds__(256) void k_wide(const float2* __restrict__ A,
                                              const float2* __restrict__ B,
                                              float2* __restrict__ C) {
  __shared__ float2 As[16][33];  // [k][i-row 0..31]
  __shared__ float2 Bs[16][65];  // [k][j 0..63]
  int i0 = blockIdx.y * 32, j0 = blockIdx.x * 64;
  int tid = threadIdx.x, tx = tid & 15, ty = tid >> 4;
  float accx[2][4] = {}, accy[2][4] = {};
  int acol = tid & 15, arow = tid >> 4;
  int bj = tid & 63, bk = tid >> 6;
  for (int k0 = 0; k0 < 256; k0 += 16) {
    __syncthreads();
#pragma unroll
    for (int r = 0; r < 2; ++r)
      As[acol][arow + 16 * r] = A[(i0 + arow + 16 * r) * 256 + k0 + acol];
#pragma unroll
    for (int r = 0; r < 4; ++r)
      Bs[bk + 4 * r][bj] = B[(size_t)(k0 + bk + 4 * r) * LL + j0 + bj];
    __syncthreads();
#pragma unroll
    for (int kk = 0; kk < 16; ++kk) {
      float2 a[2], b[4];
      a[0] = As[kk][ty];
      a[1] = As[kk][ty + 16];
#pragma unroll
      for (int c = 0; c < 4; ++c) b[c] = Bs[kk][tx + 16 * c];
#pragma unroll
      for (int r = 0; r < 2; ++r)
#pragma unroll
        for (int c = 0; c < 4; ++c) {
          accx[r][c] += a[r].x * b[c].x - a[r].y * b[c].y;
          accy[r][c] += a[r].x * b[c].y + a[r].y * b[c].x;
        }
    }
  }
#pragma unroll
  for (int r = 0; r < 2; ++r)
#pragma unroll
    for (int c = 0; c < 4; ++c)
      C[(size_t)(i0 + ty + 16 * r) * LL + j0 + tx + 16 * c] = make_float2(accx[r][c], accy[r][c]);
}

// ---------------- q,d,v,u per l ----------------
__global__ __launch_bounds__(256) void k_qduv(const float2* __restrict__ W,
                                              const float2* __restrict__ Y,
                                              const float* __restrict__ Are,
                                              const float* __restrict__ Aim,
                                              const float* __restrict__ gamma,
                                              const float* __restrict__ delta,
                                              float* __restrict__ vvec, float* __restrict__ uvec) {
  int l = blockIdx.x * 256 + threadIdx.x;
  float dacc = 0.f, qacc = 0.f;
  for (int m = 0; m < MM; ++m) {
    size_t o = (size_t)m * LL + l;
    float2 w = W[o], y = Y[o];
    dacc += w.x * Are[o] - w.y * Aim[o];
    qacc += w.x * y.x + w.y * y.y;
  }
  float v = qacc / (dacc + 1e-12f);
  float dlt = 1.0f / (1.0f + expf(-delta[0]));
  float p = gamma[l];
  vvec[l] = v;
  uvec[l] = p + dlt * (v - p);
}

// ---------------- LayerNorm over u[4096] ----------------
__global__ __launch_bounds__(256) void k_ln(const float* __restrict__ u,
                                            const float* __restrict__ lnw,
                                            const float* __restrict__ lnb,
                                            float* __restrict__ up) {
  int tid = threadIdx.x;
  float s = 0.f;
  for (int i = tid; i < LL; i += 256) s += u[i];
  float mu = blk_red_sum(s) * (1.0f / LL);
  float s2 = 0.f;
  for (int i = tid; i < LL; i += 256) { float d = u[i] - mu; s2 += d * d; }
  float var = blk_red_sum(s2) * (1.0f / LL);
  float inv = rsqrtf(var + 1e-5f);
  for (int i = tid; i < LL; i += 256) up[i] = (u[i] - mu) * inv * lnw[i] + lnb[i];
}

// ---------------- gate: g = sigmoid(gate_W @ u + gate_b) ----------------
__global__ __launch_bounds__(256) void k_gate(const float* __restrict__ Wg,
                                              const float* __restrict__ u,
                                              const float* __restrict__ gb,
                                              float* __restrict__ g) {
  int row = blockIdx.x, tid = threadIdx.x;
  const float* wr = Wg + (size_t)row * LL;
  float s = 0.f;
  for (int j = tid; j < LL; j += 256) s += wr[j] * u[j];
  float tot = blk_red_sum(s);
  if (tid == 0) g[row] = 1.0f / (1.0f + expf(-(tot + gb[row])));
}

// ---------------- attention row + final combine ----------------
__global__ __launch_bounds__(256) void k_attn(const float* __restrict__ up,
                                              const float* __restrict__ inw,
                                              const float* __restrict__ inb,
                                              const float* __restrict__ outw,
                                              const float* __restrict__ outb,
                                              const float* __restrict__ g,
                                              const float* __restrict__ v,
                                              const float* __restrict__ gamma,
                                              const float* __restrict__ lmbda,
                                              float* __restrict__ out) {
  int i = blockIdx.x, tid = threadIdx.x;
  float qv = up[i] * inw[0] + inb[0];
  float w1 = inw[1], b1 = inb[1], w2 = inw[2], b2 = inb[2];
  float mx = -3.4e38f;
  for (int j = tid; j < LL; j += 256) {
    float kv = up[j] * w1 + b1;
    mx = fmaxf(mx, qv * kv);
  }
  mx = blk_red_max(mx);
  float den = 0.f, num = 0.f;
  for (int j = tid; j < LL; j += 256) {
    float kv = up[j] * w1 + b1;
    float vv = up[j] * w2 + b2;
    float e = expf(qv * kv - mx);
    den += e;
    num += e * vv;
  }
  den = blk_red_sum(den);
  num = blk_red_sum(num);
  if (tid == 0) {
    float attn = (num / den) * outw[0] + outb[0];
    float s = g[i] * v[i] + (1.0f - g[i]) * gamma[i] + attn - lmbda[0];
    out[i] = fmaxf(s, 0.0f);
  }
}

extern "C" void kernel_launch(void* const* d_in, const int* in_sizes, int n_in,
                              void* d_out, int out_size, void* d_ws, size_t ws_size,
                              hipStream_t stream) {
  const float* gamma = (const float*)d_in[0];
  const float* Are   = (const float*)d_in[1];
  const float* Aim   = (const float*)d_in[2];
  const float* Xre   = (const float*)d_in[3];
  const float* Xim   = (const float*)d_in[4];
  const float* lnw   = (const float*)d_in[5];
  const float* lnb   = (const float*)d_in[6];
  const float* inw   = (const float*)d_in[7];
  const float* inb   = (const float*)d_in[8];
  const float* outw  = (const float*)d_in[9];
  const float* outb  = (const float*)d_in[10];
  const float* gateW = (const float*)d_in[11];
  const float* gateb = (const float*)d_in[12];
  const float* delta = (const float*)d_in[13];
  const float* lmbda = (const float*)d_in[14];
  float* out = (float*)d_out;

  float2* R   = (float2*)d_ws;        // 65536
  float2* Xa  = R + 65536;
  float2* Xb  = Xa + 65536;
  float2* Tt  = Xb + 65536;
  float2* G   = Tt + 65536;
  float2* Apk = G + 65536;            // MM*LL (aliased as Y after W is built)
  float2* W   = Apk + (size_t)MM * LL;
  float2* Y   = Apk;                  // alias: Apk dead after first k_wide
  float* vvec = (float*)(W + (size_t)MM * LL);
  float* uvec = vvec + LL;
  float* upv  = uvec + LL;
  float* gv   = upv + LL;

  k_init<<<256, 256, 0, stream>>>(R, G);
  k_pack<<<(MM * LL) / 256, 256, 0, stream>>>(Are, Aim, Apk);
  k_gram<<<dim3(16, 16), 256, 0, stream>>>(Are, Aim, gamma, LL, LL / 16, R);
  k_gram<<<dim3(16, 16), 256, 0, stream>>>(Xre, Xim, nullptr, TT, TT / 16, G);
  k_x0<<<256, 256, 0, stream>>>(R, Xa);

  float2* cur = Xa;
  float2* oth = Xb;
  for (int it = 0; it < 7; ++it) {
    k_zgemm256<<<256, 256, 0, stream>>>(R, cur, Tt, 0);     // T = R @ X
    k_zgemm256<<<256, 256, 0, stream>>>(cur, Tt, oth, 1);   // X' = 2X - X @ T
    float2* t = cur; cur = oth; oth = t;
  }

  k_wide<<<dim3(64, 8), 256, 0, stream>>>(cur, Apk, W);  // W = Rinv @ A
  k_wide<<<dim3(64, 8), 256, 0, stream>>>(G, W, Y);      // Y = G @ W (Y aliases Apk)
  k_qduv<<<16, 256, 0, stream>>>(W, Y, Are, Aim, gamma, delta, vvec, uvec);
  k_ln<<<1, 256, 0, stream>>>(uvec, lnw, lnb, upv);
  k_gate<<<LL, 256, 0, stream>>>(gateW, uvec, gateb, gv);
  k_attn<<<LL, 256, 0, stream>>>(upv, inw, inb, outw, outb, gv, vvec, gamma, lmbda, out);
}

// Round 3
// 577.266 us; speedup vs baseline: 1.0536x; 1.0536x over previous
//
#include <hip/hip_runtime.h>
#include <hip/hip_bf16.h>
#include <math.h>

#define MM 256
#define LL 4096
#define TT 2048

// ---------------- reductions ----------------
__device__ __forceinline__ float wave_red_sum(float v) {
#pragma unroll
  for (int o = 32; o > 0; o >>= 1) v += __shfl_down(v, o);
  return v;
}
__device__ __forceinline__ float wave_red_max(float v) {
#pragma unroll
  for (int o = 32; o > 0; o >>= 1) v = fmaxf(v, __shfl_down(v, o));
  return v;
}
__device__ float blk_red_sum(float v) {  // blockDim.x == 256
  __shared__ float sh[4];
  int lane = threadIdx.x & 63, wv = threadIdx.x >> 6;
  v = wave_red_sum(v);
  __syncthreads();
  if (lane == 0) sh[wv] = v;
  __syncthreads();
  return sh[0] + sh[1] + sh[2] + sh[3];
}
__device__ float blk_red_max(float v) {
  __shared__ float shm[4];
  int lane = threadIdx.x & 63, wv = threadIdx.x >> 6;
  v = wave_red_max(v);
  __syncthreads();
  if (lane == 0) shm[wv] = v;
  __syncthreads();
  return fmaxf(fmaxf(shm[0], shm[1]), fmaxf(shm[2], shm[3]));
}

// ---------------- pack A planes to float2 ----------------
__global__ __launch_bounds__(256) void k_pack(const float* __restrict__ Are,
                                              const float* __restrict__ Aim,
                                              float2* __restrict__ Apk) {
  int idx = blockIdx.x * 256 + threadIdx.x;  // MM*LL
  Apk[idx] = make_float2(Are[idx], Aim[idx]);
}

// ---------------- Hermitian gram partials ----------------
// C[i,j] = sum_k alpha[k]*U[i,k]*conj(U[j,k]); only lower tiles (ti>=tj).
// grid (10, S), Kc = K/S. Partials to P[(ks*10 + t)*4096 + loc].
__global__ __launch_bounds__(256) void k_gram2(const float* __restrict__ Ure,
                                               const float* __restrict__ Uim,
                                               const float* __restrict__ alpha,
                                               int K, int Kc, float2* __restrict__ P) {
  __shared__ float2 Uc[64][33];
  __shared__ float2 Vc[64][33];
  const int ti_lu[10] = {0, 1, 1, 2, 2, 2, 3, 3, 3, 3};
  const int tj_lu[10] = {0, 0, 1, 0, 1, 2, 0, 1, 2, 3};
  int t = blockIdx.x;
  int i0 = ti_lu[t] * 64, j0 = tj_lu[t] * 64;
  int k0 = blockIdx.y * Kc;
  int tid = threadIdx.x;
  int lrow = tid >> 2, lq = tid & 3;
  int tx = tid & 15, ty = tid >> 4;
  float accx[4][4] = {}, accy[4][4] = {};
  for (int kb = 0; kb < Kc; kb += 32) {
    __syncthreads();
#pragma unroll
    for (int h = 0; h < 2; ++h) {
      int kq = lq + 4 * h;          // 0..7 float4 slot within 32-wide chunk
      int kg = k0 + kb + kq * 4;
      float4 ur = *(const float4*)&Ure[(size_t)(i0 + lrow) * K + kg];
      float4 ui = *(const float4*)&Uim[(size_t)(i0 + lrow) * K + kg];
      if (alpha) {
        float4 al = *(const float4*)&alpha[kg];
        ur.x *= al.x; ur.y *= al.y; ur.z *= al.z; ur.w *= al.w;
        ui.x *= al.x; ui.y *= al.y; ui.z *= al.z; ui.w *= al.w;
      }
      float2* up = &Uc[lrow][kq * 4];
      up[0] = make_float2(ur.x, ui.x);
      up[1] = make_float2(ur.y, ui.y);
      up[2] = make_float2(ur.z, ui.z);
      up[3] = make_float2(ur.w, ui.w);
      float4 vr = *(const float4*)&Ure[(size_t)(j0 + lrow) * K + kg];
      float4 vi = *(const float4*)&Uim[(size_t)(j0 + lrow) * K + kg];
      float2* vp = &Vc[lrow][kq * 4];
      vp[0] = make_float2(vr.x, vi.x);
      vp[1] = make_float2(vr.y, vi.y);
      vp[2] = make_float2(vr.z, vi.z);
      vp[3] = make_float2(vr.w, vi.w);
    }
    __syncthreads();
#pragma unroll 8
    for (int kk = 0; kk < 32; ++kk) {
      float2 a[4], b[4];
#pragma unroll
      for (int r = 0; r < 4; ++r) a[r] = Uc[ty + 16 * r][kk];
#pragma unroll
      for (int c = 0; c < 4; ++c) b[c] = Vc[tx + 16 * c][kk];
#pragma unroll
      for (int r = 0; r < 4; ++r)
#pragma unroll
        for (int c = 0; c < 4; ++c) {
          accx[r][c] += a[r].x * b[c].x + a[r].y * b[c].y;
          accy[r][c] += a[r].y * b[c].x - a[r].x * b[c].y;
        }
    }
  }
  float2* dst = P + ((size_t)blockIdx.y * 10 + t) * 4096;
#pragma unroll
  for (int r = 0; r < 4; ++r)
#pragma unroll
    for (int c = 0; c < 4; ++c)
      dst[(ty + 16 * r) * 64 + tx + 16 * c] = make_float2(accx[r][c], accy[r][c]);
}

// ---------------- reduce partials + Hermitian mirror + ridge ----------------
__global__ __launch_bounds__(256) void k_gram_red(const float2* __restrict__ P, int S,
                                                  float ridge, float2* __restrict__ C) {
  int idx = blockIdx.x * 256 + threadIdx.x;  // 65536
  int i = idx >> 8, j = idx & 255;
  int ti = i >> 6, tj = j >> 6;
  bool lower = (ti >= tj);
  int a = lower ? ti : tj, b = lower ? tj : ti;
  int t = a * (a + 1) / 2 + b;
  int li = lower ? (i & 63) : (j & 63);
  int lj = lower ? (j & 63) : (i & 63);
  const float2* p = P + (size_t)t * 4096 + li * 64 + lj;
  float re = 0.f, im = 0.f;
  for (int s = 0; s < S; ++s) {
    float2 v = p[(size_t)s * 10 * 4096];
    re += v.x;
    im += v.y;
  }
  if (!lower) im = -im;
  if (i == j) re += ridge;
  C[idx] = make_float2(re, im);
}

// ---------------- Newton X0 = diag(R)^-1 ----------------
__global__ __launch_bounds__(256) void k_x0(const float2* __restrict__ R, float2* __restrict__ X) {
  int idx = blockIdx.x * 256 + threadIdx.x;
  int i = idx >> 8, j = idx & 255;
  float v = (i == j) ? (1.0f / R[i * 257].x) : 0.0f;
  X[idx] = make_float2(v, 0.0f);
}

// ---------------- 256x256x256 complex matmul; mode1: C = 2A - A@B ----------------
__global__ __launch_bounds__(256) void k_zgemm256(const float2* __restrict__ A,
                                                  const float2* __restrict__ B,
                                                  float2* __restrict__ C, int mode) {
  __shared__ float2 As[16][17], Bs[16][17];
  int bi = blockIdx.x >> 4, bj = blockIdx.x & 15;
  int i0 = bi * 16, j0 = bj * 16;
  int tx = threadIdx.x & 15, ty = threadIdx.x >> 4;
  float accx = 0.f, accy = 0.f;
  for (int k0 = 0; k0 < 256; k0 += 16) {
    __syncthreads();
    As[ty][tx] = A[(i0 + ty) * 256 + k0 + tx];
    Bs[ty][tx] = B[(k0 + ty) * 256 + j0 + tx];
    __syncthreads();
#pragma unroll
    for (int kk = 0; kk < 16; ++kk) {
      float2 a = As[ty][kk], b = Bs[kk][tx];
      accx += a.x * b.x - a.y * b.y;
      accy += a.x * b.y + a.y * b.x;
    }
  }
  int idx = (i0 + ty) * 256 + j0 + tx;
  if (mode) {
    float2 x = A[idx];
    accx = 2.0f * x.x - accx;
    accy = 2.0f * x.y - accy;
  }
  C[idx] = make_float2(accx, accy);
}

// ---------------- wide complex matmul: C[256 x 4096] = A[256x256] @ B[256x4096] ----------------
// tile 32(i) x 64(j); grid (64, 8)
__global__ __launch_bounds__(256) void k_wide(const float2* __restrict__ A,
                                              const float2* __restrict__ B,
                                              float2* __restrict__ C) {
  __shared__ float2 As[16][33];  // [k][i-row 0..31]
  __shared__ float2 Bs[16][65];  // [k][j 0..63]
  int i0 = blockIdx.y * 32, j0 = blockIdx.x * 64;
  int tid = threadIdx.x, tx = tid & 15, ty = tid >> 4;
  float accx[2][4] = {}, accy[2][4] = {};
  int acol = tid & 15, arow = tid >> 4;
  int bj = tid & 63, bk = tid >> 6;
  for (int k0 = 0; k0 < 256; k0 += 16) {
    __syncthreads();
#pragma unroll
    for (int r = 0; r < 2; ++r)
      As[acol][arow + 16 * r] = A[(i0 + arow + 16 * r) * 256 + k0 + acol];
#pragma unroll
    for (int r = 0; r < 4; ++r)
      Bs[bk + 4 * r][bj] = B[(size_t)(k0 + bk + 4 * r) * LL + j0 + bj];
    __syncthreads();
#pragma unroll
    for (int kk = 0; kk < 16; ++kk) {
      float2 a[2], b[4];
      a[0] = As[kk][ty];
      a[1] = As[kk][ty + 16];
#pragma unroll
      for (int c = 0; c < 4; ++c) b[c] = Bs[kk][tx + 16 * c];
#pragma unroll
      for (int r = 0; r < 2; ++r)
#pragma unroll
        for (int c = 0; c < 4; ++c) {
          accx[r][c] += a[r].x * b[c].x - a[r].y * b[c].y;
          accy[r][c] += a[r].x * b[c].y + a[r].y * b[c].x;
        }
    }
  }
#pragma unroll
  for (int r = 0; r < 2; ++r)
#pragma unroll
    for (int c = 0; c < 4; ++c)
      C[(size_t)(i0 + ty + 16 * r) * LL + j0 + tx + 16 * c] = make_float2(accx[r][c], accy[r][c]);
}

// ---------------- q,d,v,u per l ----------------
__global__ __launch_bounds__(256) void k_qduv(const float2* __restrict__ W,
                                              const float2* __restrict__ Y,
                                              const float* __restrict__ Are,
                                              const float* __restrict__ Aim,
                                              const float* __restrict__ gamma,
                                              const float* __restrict__ delta,
                                              float* __restrict__ vvec, float* __restrict__ uvec) {
  int l = blockIdx.x * 256 + threadIdx.x;
  float dacc = 0.f, qacc = 0.f;
  for (int m = 0; m < MM; ++m) {
    size_t o = (size_t)m * LL + l;
    float2 w = W[o], y = Y[o];
    dacc += w.x * Are[o] - w.y * Aim[o];
    qacc += w.x * y.x + w.y * y.y;
  }
  float v = qacc / (dacc + 1e-12f);
  float dlt = 1.0f / (1.0f + expf(-delta[0]));
  float p = gamma[l];
  vvec[l] = v;
  uvec[l] = p + dlt * (v - p);
}

// ---------------- LayerNorm over u[4096] ----------------
__global__ __launch_bounds__(256) void k_ln(const float* __restrict__ u,
                                            const float* __restrict__ lnw,
                                            const float* __restrict__ lnb,
                                            float* __restrict__ up) {
  int tid = threadIdx.x;
  float s = 0.f;
  for (int i = tid; i < LL; i += 256) s += u[i];
  float mu = blk_red_sum(s) * (1.0f / LL);
  float s2 = 0.f;
  for (int i = tid; i < LL; i += 256) { float d = u[i] - mu; s2 += d * d; }
  float var = blk_red_sum(s2) * (1.0f / LL);
  float inv = rsqrtf(var + 1e-5f);
  for (int i = tid; i < LL; i += 256) up[i] = (u[i] - mu) * inv * lnw[i] + lnb[i];
}

// ---------------- gate: g = sigmoid(gate_W @ u + gate_b) ----------------
__global__ __launch_bounds__(256) void k_gate(const float* __restrict__ Wg,
                                              const float* __restrict__ u,
                                              const float* __restrict__ gb,
                                              float* __restrict__ g) {
  int row = blockIdx.x, tid = threadIdx.x;
  const float4* wr = (const float4*)(Wg + (size_t)row * LL);
  const float4* u4 = (const float4*)u;
  float s = 0.f;
  for (int j = tid; j < LL / 4; j += 256) {
    float4 w = wr[j], x = u4[j];
    s += w.x * x.x + w.y * x.y + w.z * x.z + w.w * x.w;
  }
  float tot = blk_red_sum(s);
  if (tid == 0) g[row] = 1.0f / (1.0f + expf(-(tot + gb[row])));
}

// ---------------- attention row + final combine ----------------
__global__ __launch_bounds__(256) void k_attn(const float* __restrict__ up,
                                              const float* __restrict__ inw,
                                              const float* __restrict__ inb,
                                              const float* __restrict__ outw,
                                              const float* __restrict__ outb,
                                              const float* __restrict__ g,
                                              const float* __restrict__ v,
                                              const float* __restrict__ gamma,
                                              const float* __restrict__ lmbda,
                                              float* __restrict__ out) {
  int i = blockIdx.x, tid = threadIdx.x;
  float qv = up[i] * inw[0] + inb[0];
  float w1 = inw[1], b1 = inb[1], w2 = inw[2], b2 = inb[2];
  const float4* up4 = (const float4*)up;
  float mx = -3.4e38f;
  for (int j = tid; j < LL / 4; j += 256) {
    float4 u = up4[j];
    mx = fmaxf(mx, fmaxf(fmaxf(qv * (u.x * w1 + b1), qv * (u.y * w1 + b1)),
                         fmaxf(qv * (u.z * w1 + b1), qv * (u.w * w1 + b1))));
  }
  mx = blk_red_max(mx);
  float den = 0.f, num = 0.f;
  for (int j = tid; j < LL / 4; j += 256) {
    float4 u = up4[j];
    float e0 = expf(qv * (u.x * w1 + b1) - mx);
    float e1 = expf(qv * (u.y * w1 + b1) - mx);
    float e2 = expf(qv * (u.z * w1 + b1) - mx);
    float e3 = expf(qv * (u.w * w1 + b1) - mx);
    den += e0 + e1 + e2 + e3;
    num += e0 * (u.x * w2 + b2) + e1 * (u.y * w2 + b2) + e2 * (u.z * w2 + b2) + e3 * (u.w * w2 + b2);
  }
  den = blk_red_sum(den);
  num = blk_red_sum(num);
  if (tid == 0) {
    float attn = (num / den) * outw[0] + outb[0];
    float s = g[i] * v[i] + (1.0f - g[i]) * gamma[i] + attn - lmbda[0];
    out[i] = fmaxf(s, 0.0f);
  }
}

extern "C" void kernel_launch(void* const* d_in, const int* in_sizes, int n_in,
                              void* d_out, int out_size, void* d_ws, size_t ws_size,
                              hipStream_t stream) {
  const float* gamma = (const float*)d_in[0];
  const float* Are   = (const float*)d_in[1];
  const float* Aim   = (const float*)d_in[2];
  const float* Xre   = (const float*)d_in[3];
  const float* Xim   = (const float*)d_in[4];
  const float* lnw   = (const float*)d_in[5];
  const float* lnb   = (const float*)d_in[6];
  const float* inw   = (const float*)d_in[7];
  const float* inb   = (const float*)d_in[8];
  const float* outw  = (const float*)d_in[9];
  const float* outb  = (const float*)d_in[10];
  const float* gateW = (const float*)d_in[11];
  const float* gateb = (const float*)d_in[12];
  const float* delta = (const float*)d_in[13];
  const float* lmbda = (const float*)d_in[14];
  float* out = (float*)d_out;

  // K-splits chosen so phase-1 partials fit INSIDE the phase-2 region:
  // PA+PX = (32+16)*10*4096 = 1,966,080 f2  <  Apk+W = 2,097,152 f2.
  // Total ws usage identical to the round-1 passing kernel (~19.5 MB).
  const int SA = 32;  // Kc = 128
  const int SX = 16;  // Kc = 128

  float2* R  = (float2*)d_ws;      // 65536 f2 each
  float2* Xa = R + 65536;
  float2* Xb = Xa + 65536;
  float2* Tt = Xb + 65536;
  float2* G  = Tt + 65536;
  float2* BIG = G + 65536;
  // phase 1 (gram partials):
  float2* PA = BIG;                          // 32*10*4096 = 1,310,720 f2
  float2* PX = BIG + (size_t)SA * 10 * 4096; // 16*10*4096 =   655,360 f2
  // phase 2 (PA/PX dead after the reduces):
  float2* Apk = BIG;                         // 1,048,576 f2
  float2* W   = BIG + 1048576;               // 1,048,576 f2
  float2* Y   = Apk;                         // alias: Apk dead after first k_wide
  float* vvec = (float*)(BIG + 2097152);
  float* uvec = vvec + LL;
  float* upv  = uvec + LL;
  float* gv   = upv + LL;

  k_gram2<<<dim3(10, SA), 256, 0, stream>>>(Are, Aim, gamma, LL, LL / SA, PA);
  k_gram2<<<dim3(10, SX), 256, 0, stream>>>(Xre, Xim, nullptr, TT, TT / SX, PX);
  k_gram_red<<<256, 256, 0, stream>>>(PA, SA, 0.01f, R);
  k_gram_red<<<256, 256, 0, stream>>>(PX, SX, 0.0f, G);
  k_pack<<<(MM * LL) / 256, 256, 0, stream>>>(Are, Aim, Apk);
  k_x0<<<256, 256, 0, stream>>>(R, Xa);

  float2* cur = Xa;
  float2* oth = Xb;
  for (int it = 0; it < 6; ++it) {
    k_zgemm256<<<256, 256, 0, stream>>>(R, cur, Tt, 0);     // T = R @ X
    k_zgemm256<<<256, 256, 0, stream>>>(cur, Tt, oth, 1);   // X' = 2X - X @ T
    float2* t = cur; cur = oth; oth = t;
  }

  k_wide<<<dim3(64, 8), 256, 0, stream>>>(cur, Apk, W);  // W = Rinv @ A
  k_wide<<<dim3(64, 8), 256, 0, stream>>>(G, W, Y);      // Y = G @ W
  k_qduv<<<16, 256, 0, stream>>>(W, Y, Are, Aim, gamma, delta, vvec, uvec);
  k_ln<<<1, 256, 0, stream>>>(uvec, lnw, lnb, upv);
  k_gate<<<LL, 256, 0, stream>>>(gateW, uvec, gateb, gv);
  k_attn<<<LL, 256, 0, stream>>>(upv, inw, inb, outw, outb, gv, vvec, gamma, lmbda, out);
}

// Round 4
// 448.380 us; speedup vs baseline: 1.3565x; 1.2874x over previous
//
#include <hip/hip_runtime.h>
#include <hip/hip_bf16.h>
#include <math.h>

#define MM 256
#define LL 4096
#define TT 2048

typedef __attribute__((ext_vector_type(8))) short bf16x8;
typedef __attribute__((ext_vector_type(4))) float f32x4;
typedef unsigned short ushort_t;

#define MFMA3(ACC, AH, AL, BH, BL)                                              \
  ACC = __builtin_amdgcn_mfma_f32_16x16x32_bf16(AH, BH, ACC, 0, 0, 0);          \
  ACC = __builtin_amdgcn_mfma_f32_16x16x32_bf16(AH, BL, ACC, 0, 0, 0);          \
  ACC = __builtin_amdgcn_mfma_f32_16x16x32_bf16(AL, BH, ACC, 0, 0, 0);

__device__ __forceinline__ void split_bf16(float x, ushort_t& h, ushort_t& l) {
  __hip_bfloat16 bh = __float2bfloat16(x);
  h = *(ushort_t*)&bh;
  __hip_bfloat16 bl = __float2bfloat16(x - __bfloat162float(bh));
  l = *(ushort_t*)&bl;
}

// ---------------- reductions ----------------
__device__ __forceinline__ float wave_red_sum(float v) {
#pragma unroll
  for (int o = 32; o > 0; o >>= 1) v += __shfl_down(v, o);
  return v;
}
__device__ __forceinline__ float wave_red_max(float v) {
#pragma unroll
  for (int o = 32; o > 0; o >>= 1) v = fmaxf(v, __shfl_down(v, o));
  return v;
}
__device__ float blk_red_sum(float v) {
  __shared__ float sh[4];
  int lane = threadIdx.x & 63, wv = threadIdx.x >> 6;
  v = wave_red_sum(v);
  __syncthreads();
  if (lane == 0) sh[wv] = v;
  __syncthreads();
  return sh[0] + sh[1] + sh[2] + sh[3];
}
__device__ float blk_red_max(float v) {
  __shared__ float shm[4];
  int lane = threadIdx.x & 63, wv = threadIdx.x >> 6;
  v = wave_red_max(v);
  __syncthreads();
  if (lane == 0) shm[wv] = v;
  __syncthreads();
  return fmaxf(fmaxf(shm[0], shm[1]), fmaxf(shm[2], shm[3]));
}

// ---------------- zero/init: R=ridge*I, G=0, q=d=0 ----------------
// floats [0,131072): R; [131072,262144): G; [262144,266240): q; [266240,270336): d
__global__ __launch_bounds__(256) void k_zero(float* __restrict__ ws) {
  int idx = blockIdx.x * 256 + threadIdx.x;  // 270336 total
  float v = 0.0f;
  if (idx < 131072 && (idx % 514) == 0) v = 0.01f;  // R diag .x slots
  ws[idx] = v;
}

// ---------------- fp32 -> split-bf16 planes (optional sqrt(alpha) col scale) ----------
__global__ __launch_bounds__(256) void k_conv(const float* __restrict__ re,
                                              const float* __restrict__ im,
                                              const float* __restrict__ alpha,
                                              int kmask, ushort_t* __restrict__ dst,
                                              int PS) {
  int idx = blockIdx.x * 256 + threadIdx.x;
  float s = alpha ? sqrtf(alpha[idx & kmask]) : 1.0f;
  ushort_t h, l;
  split_bf16(re[idx] * s, h, l);
  dst[idx] = h;
  dst[idx + PS] = l;
  split_bf16(im[idx] * s, h, l);
  dst[idx + 2 * PS] = h;
  dst[idx + 3 * PS] = l;
}

// ---------------- 256x256 float2 -> split-bf16 planes ----------------
__global__ __launch_bounds__(256) void k_conv256(const float2* __restrict__ src,
                                                 ushort_t* __restrict__ dst) {
  int idx = blockIdx.x * 256 + threadIdx.x;  // 65536
  float2 v = src[idx];
  ushort_t h, l;
  split_bf16(v.x, h, l);
  dst[idx] = h;
  dst[idx + 65536] = l;
  split_bf16(v.y, h, l);
  dst[idx + 131072] = h;
  dst[idx + 196608] = l;
}

// ---------------- transpose fp32 planes [256][4096] -> split-bf16 planes [4096][256] ----
__global__ __launch_bounds__(256) void k_transpA(const float* __restrict__ re,
                                                 const float* __restrict__ im,
                                                 ushort_t* __restrict__ dst) {
  __shared__ float tr[32][33], ti[32][33];
  int c0 = blockIdx.x * 32, r0 = blockIdx.y * 32;
  int tx = threadIdx.x & 31, tg = threadIdx.x >> 5;
#pragma unroll
  for (int i = 0; i < 4; ++i) {
    int r = tg + 8 * i;
    tr[r][tx] = re[(size_t)(r0 + r) * LL + c0 + tx];
    ti[r][tx] = im[(size_t)(r0 + r) * LL + c0 + tx];
  }
  __syncthreads();
#pragma unroll
  for (int i = 0; i < 4; ++i) {
    int rr = tg + 8 * i;
    size_t o = (size_t)(c0 + rr) * 256 + r0 + tx;
    ushort_t h, l;
    split_bf16(tr[tx][rr], h, l);
    dst[o] = h;
    dst[o + 1048576] = l;
    split_bf16(ti[tx][rr], h, l);
    dst[o + 2097152] = h;
    dst[o + 3145728] = l;
  }
}

// ---------------- transpose float2 [256][4096] -> split-bf16 planes [4096][256] --------
__global__ __launch_bounds__(256) void k_transpW(const float2* __restrict__ W,
                                                 ushort_t* __restrict__ dst) {
  __shared__ float tr[32][33], ti[32][33];
  int c0 = blockIdx.x * 32, r0 = blockIdx.y * 32;
  int tx = threadIdx.x & 31, tg = threadIdx.x >> 5;
#pragma unroll
  for (int i = 0; i < 4; ++i) {
    int r = tg + 8 * i;
    float2 w = W[(size_t)(r0 + r) * LL + c0 + tx];
    tr[r][tx] = w.x;
    ti[r][tx] = w.y;
  }
  __syncthreads();
#pragma unroll
  for (int i = 0; i < 4; ++i) {
    int rr = tg + 8 * i;
    size_t o = (size_t)(c0 + rr) * 256 + r0 + tx;
    ushort_t h, l;
    split_bf16(tr[tx][rr], h, l);
    dst[o] = h;
    dst[o + 1048576] = l;
    split_bf16(ti[tx][rr], h, l);
    dst[o + 2097152] = h;
    dst[o + 3145728] = l;
  }
}

// ---------------- MFMA gram: C += P * P^H (planes row-major [256][K]) ----------------
// grid (16 tiles of 64x64, KS); atomicAdd fp32.
__global__ __launch_bounds__(256) void k_gram_mfma(const ushort_t* __restrict__ pl, int PS,
                                                   int K, int Kc, float* __restrict__ C) {
  const ushort_t* prh = pl;
  const ushort_t* prl = pl + PS;
  const ushort_t* pih = pl + 2 * (size_t)PS;
  const ushort_t* pil = pl + 3 * (size_t)PS;
  int i0 = (blockIdx.x >> 2) * 64, j0 = (blockIdx.x & 3) * 64;
  int lane = threadIdx.x & 63, wv = threadIdx.x >> 6;
  int m = i0 + wv * 16 + (lane & 15);
  int kq = (lane >> 4) * 8;
  f32x4 z = {0.f, 0.f, 0.f, 0.f};
  f32x4 Zrr[4], Zri[4], Zir[4], Zii[4];
#pragma unroll
  for (int s = 0; s < 4; ++s) { Zrr[s] = z; Zri[s] = z; Zir[s] = z; Zii[s] = z; }
  int kbeg = blockIdx.y * Kc;
  for (int k0 = kbeg; k0 < kbeg + Kc; k0 += 32) {
    size_t ao = (size_t)m * K + k0 + kq;
    bf16x8 arh = *(const bf16x8*)(prh + ao);
    bf16x8 arl = *(const bf16x8*)(prl + ao);
    bf16x8 aih = *(const bf16x8*)(pih + ao);
    bf16x8 ail = *(const bf16x8*)(pil + ao);
#pragma unroll
    for (int s = 0; s < 4; ++s) {
      size_t bo = (size_t)(j0 + s * 16 + (lane & 15)) * K + k0 + kq;
      bf16x8 brh = *(const bf16x8*)(prh + bo);
      bf16x8 brl = *(const bf16x8*)(prl + bo);
      bf16x8 bih = *(const bf16x8*)(pih + bo);
      bf16x8 bil = *(const bf16x8*)(pil + bo);
      MFMA3(Zrr[s], arh, arl, brh, brl);
      MFMA3(Zri[s], arh, arl, bih, bil);
      MFMA3(Zir[s], aih, ail, brh, brl);
      MFMA3(Zii[s], aih, ail, bih, bil);
    }
  }
  int rbase = i0 + wv * 16 + (lane >> 4) * 4;
#pragma unroll
  for (int s = 0; s < 4; ++s) {
    int col = j0 + s * 16 + (lane & 15);
#pragma unroll
    for (int r = 0; r < 4; ++r) {
      float re = Zrr[s][r] + Zii[s][r];   // a * conj(b)
      float im = Zir[s][r] - Zri[s][r];
      float* p = C + ((size_t)(rbase + r) * 256 + col) * 2;
      atomicAdd(p, re);
      atomicAdd(p + 1, im);
    }
  }
}

// ---------------- MFMA wide: C[256x4096] = A(256x256) @ B(256x4096) ----------------
// Ap: planes [256][256]; Bp: planes [4096][256] (B^T layout).
// mode 0: write Cout (=W) + d[l] += Re(W .* A)  (reload Are/Aim)
// mode 1: no C write;  q[l] += Re(conj(W) .* Y) (reload W)
__global__ __launch_bounds__(256) void k_wide_mfma(const ushort_t* __restrict__ Ap,
                                                   const ushort_t* __restrict__ Bp,
                                                   const float* __restrict__ AuxRe,
                                                   const float* __restrict__ AuxIm,
                                                   const float2* __restrict__ Wf,
                                                   float2* __restrict__ Cout,
                                                   float* __restrict__ dq, int mode) {
  const ushort_t* arh_p = Ap;
  const ushort_t* arl_p = Ap + 65536;
  const ushort_t* aih_p = Ap + 131072;
  const ushort_t* ail_p = Ap + 196608;
  const ushort_t* brh_p = Bp;
  const ushort_t* brl_p = Bp + 1048576;
  const ushort_t* bih_p = Bp + 2097152;
  const ushort_t* bil_p = Bp + 3145728;
  int j0 = blockIdx.x * 64;  // l
  int i0 = blockIdx.y * 64;  // m
  int lane = threadIdx.x & 63, wv = threadIdx.x >> 6;
  int m = i0 + wv * 16 + (lane & 15);
  int kq = (lane >> 4) * 8;
  f32x4 z = {0.f, 0.f, 0.f, 0.f};
  f32x4 Zrr[4], Zri[4], Zir[4], Zii[4];
#pragma unroll
  for (int s = 0; s < 4; ++s) { Zrr[s] = z; Zri[s] = z; Zir[s] = z; Zii[s] = z; }
  for (int k0 = 0; k0 < 256; k0 += 32) {
    size_t ao = (size_t)m * 256 + k0 + kq;
    bf16x8 arh = *(const bf16x8*)(arh_p + ao);
    bf16x8 arl = *(const bf16x8*)(arl_p + ao);
    bf16x8 aih = *(const bf16x8*)(aih_p + ao);
    bf16x8 ail = *(const bf16x8*)(ail_p + ao);
#pragma unroll
    for (int s = 0; s < 4; ++s) {
      size_t bo = (size_t)(j0 + s * 16 + (lane & 15)) * 256 + k0 + kq;
      bf16x8 brh = *(const bf16x8*)(brh_p + bo);
      bf16x8 brl = *(const bf16x8*)(brl_p + bo);
      bf16x8 bih = *(const bf16x8*)(bih_p + bo);
      bf16x8 bil = *(const bf16x8*)(bil_p + bo);
      MFMA3(Zrr[s], arh, arl, brh, brl);
      MFMA3(Zri[s], arh, arl, bih, bil);
      MFMA3(Zir[s], aih, ail, brh, brl);
      MFMA3(Zii[s], aih, ail, bih, bil);
    }
  }
  int rbase = i0 + wv * 16 + (lane >> 4) * 4;
#pragma unroll
  for (int s = 0; s < 4; ++s) {
    int col = j0 + s * 16 + (lane & 15);
    float part = 0.f;
#pragma unroll
    for (int r = 0; r < 4; ++r) {
      float re = Zrr[s][r] - Zii[s][r];   // a * b (no conj)
      float im = Zri[s][r] + Zir[s][r];
      size_t o = (size_t)(rbase + r) * LL + col;
      if (mode == 0) {
        Cout[o] = make_float2(re, im);
        part += re * AuxRe[o] - im * AuxIm[o];
      } else {
        float2 w = Wf[o];
        part += w.x * re + w.y * im;
      }
    }
    part += __shfl_down(part, 32);
    part += __shfl_down(part, 16);
    if ((lane >> 4) == 0) atomicAdd(dq + col, part);
  }
}

// ---------------- Newton X0 = diag(R)^-1 ----------------
__global__ __launch_bounds__(256) void k_x0(const float2* __restrict__ R, float2* __restrict__ X) {
  int idx = blockIdx.x * 256 + threadIdx.x;
  int i = idx >> 8, j = idx & 255;
  float v = (i == j) ? (1.0f / R[i * 257].x) : 0.0f;
  X[idx] = make_float2(v, 0.0f);
}

// ---------------- 256x256x256 complex matmul; mode1: C = 2A - A@B ----------------
__global__ __launch_bounds__(256) void k_zgemm256(const float2* __restrict__ A,
                                                  const float2* __restrict__ B,
                                                  float2* __restrict__ C, int mode) {
  __shared__ float2 As[16][17], Bs[16][17];
  int bi = blockIdx.x >> 4, bj = blockIdx.x & 15;
  int i0 = bi * 16, j0 = bj * 16;
  int tx = threadIdx.x & 15, ty = threadIdx.x >> 4;
  float accx = 0.f, accy = 0.f;
  for (int k0 = 0; k0 < 256; k0 += 16) {
    __syncthreads();
    As[ty][tx] = A[(i0 + ty) * 256 + k0 + tx];
    Bs[ty][tx] = B[(k0 + ty) * 256 + j0 + tx];
    __syncthreads();
#pragma unroll
    for (int kk = 0; kk < 16; ++kk) {
      float2 a = As[ty][kk], b = Bs[kk][tx];
      accx += a.x * b.x - a.y * b.y;
      accy += a.x * b.y + a.y * b.x;
    }
  }
  int idx = (i0 + ty) * 256 + j0 + tx;
  if (mode) {
    float2 x = A[idx];
    accx = 2.0f * x.x - accx;
    accy = 2.0f * x.y - accy;
  }
  C[idx] = make_float2(accx, accy);
}

// ---------------- v,u from q,d ----------------
__global__ __launch_bounds__(256) void k_uv(const float* __restrict__ q,
                                            const float* __restrict__ d,
                                            const float* __restrict__ gamma,
                                            const float* __restrict__ delta,
                                            float* __restrict__ vvec, float* __restrict__ uvec) {
  int l = blockIdx.x * 256 + threadIdx.x;
  float v = q[l] / (d[l] + 1e-12f);
  float dlt = 1.0f / (1.0f + expf(-delta[0]));
  float p = gamma[l];
  vvec[l] = v;
  uvec[l] = p + dlt * (v - p);
}

// ---------------- LayerNorm over u[4096] ----------------
__global__ __launch_bounds__(256) void k_ln(const float* __restrict__ u,
                                            const float* __restrict__ lnw,
                                            const float* __restrict__ lnb,
                                            float* __restrict__ up) {
  int tid = threadIdx.x;
  float s = 0.f;
  for (int i = tid; i < LL; i += 256) s += u[i];
  float mu = blk_red_sum(s) * (1.0f / LL);
  float s2 = 0.f;
  for (int i = tid; i < LL; i += 256) { float d = u[i] - mu; s2 += d * d; }
  float var = blk_red_sum(s2) * (1.0f / LL);
  float inv = rsqrtf(var + 1e-5f);
  for (int i = tid; i < LL; i += 256) up[i] = (u[i] - mu) * inv * lnw[i] + lnb[i];
}

// ---------------- gate ----------------
__global__ __launch_bounds__(256) void k_gate(const float* __restrict__ Wg,
                                              const float* __restrict__ u,
                                              const float* __restrict__ gb,
                                              float* __restrict__ g) {
  int row = blockIdx.x, tid = threadIdx.x;
  const float4* wr = (const float4*)(Wg + (size_t)row * LL);
  const float4* u4 = (const float4*)u;
  float s = 0.f;
  for (int j = tid; j < LL / 4; j += 256) {
    float4 w = wr[j], x = u4[j];
    s += w.x * x.x + w.y * x.y + w.z * x.z + w.w * x.w;
  }
  float tot = blk_red_sum(s);
  if (tid == 0) g[row] = 1.0f / (1.0f + expf(-(tot + gb[row])));
}

// ---------------- attention row + final combine ----------------
__global__ __launch_bounds__(256) void k_attn(const float* __restrict__ up,
                                              const float* __restrict__ inw,
                                              const float* __restrict__ inb,
                                              const float* __restrict__ outw,
                                              const float* __restrict__ outb,
                                              const float* __restrict__ g,
                                              const float* __restrict__ v,
                                              const float* __restrict__ gamma,
                                              const float* __restrict__ lmbda,
                                              float* __restrict__ out) {
  int i = blockIdx.x, tid = threadIdx.x;
  float qv = up[i] * inw[0] + inb[0];
  float w1 = inw[1], b1 = inb[1], w2 = inw[2], b2 = inb[2];
  const float4* up4 = (const float4*)up;
  float mx = -3.4e38f;
  for (int j = tid; j < LL / 4; j += 256) {
    float4 u = up4[j];
    mx = fmaxf(mx, fmaxf(fmaxf(qv * (u.x * w1 + b1), qv * (u.y * w1 + b1)),
                         fmaxf(qv * (u.z * w1 + b1), qv * (u.w * w1 + b1))));
  }
  mx = blk_red_max(mx);
  float den = 0.f, num = 0.f;
  for (int j = tid; j < LL / 4; j += 256) {
    float4 u = up4[j];
    float e0 = expf(qv * (u.x * w1 + b1) - mx);
    float e1 = expf(qv * (u.y * w1 + b1) - mx);
    float e2 = expf(qv * (u.z * w1 + b1) - mx);
    float e3 = expf(qv * (u.w * w1 + b1) - mx);
    den += e0 + e1 + e2 + e3;
    num += e0 * (u.x * w2 + b2) + e1 * (u.y * w2 + b2) + e2 * (u.z * w2 + b2) + e3 * (u.w * w2 + b2);
  }
  den = blk_red_sum(den);
  num = blk_red_sum(num);
  if (tid == 0) {
    float attn = (num / den) * outw[0] + outb[0];
    float s = g[i] * v[i] + (1.0f - g[i]) * gamma[i] + attn - lmbda[0];
    out[i] = fmaxf(s, 0.0f);
  }
}

extern "C" void kernel_launch(void* const* d_in, const int* in_sizes, int n_in,
                              void* d_out, int out_size, void* d_ws, size_t ws_size,
                              hipStream_t stream) {
  const float* gamma = (const float*)d_in[0];
  const float* Are   = (const float*)d_in[1];
  const float* Aim   = (const float*)d_in[2];
  const float* Xre   = (const float*)d_in[3];
  const float* Xim   = (const float*)d_in[4];
  const float* lnw   = (const float*)d_in[5];
  const float* lnb   = (const float*)d_in[6];
  const float* inw   = (const float*)d_in[7];
  const float* inb   = (const float*)d_in[8];
  const float* outw  = (const float*)d_in[9];
  const float* outb  = (const float*)d_in[10];
  const float* gateW = (const float*)d_in[11];
  const float* gateb = (const float*)d_in[12];
  const float* delta = (const float*)d_in[13];
  const float* lmbda = (const float*)d_in[14];
  float* out = (float*)d_out;

  // Workspace layout (float offsets). Total = 4,743,168 floats = 18.97 MB
  // (<= 19.46 MB proven-safe footprint from the round-1/3 passing runs).
  float* ws = (float*)d_ws;
  float*  Rf    = ws;                        // float2[65536]  (131072 fl)
  float*  Gf    = ws + 131072;               // float2[65536]
  float*  qv_   = ws + 262144;               // [4096]
  float*  dv_   = ws + 266240;               // [4096]
  float*  vvec  = ws + 270336;
  float*  uvec  = ws + 274432;
  float*  upv   = ws + 278528;
  float*  gv    = ws + 282624;
  ushort_t* Rinvp = (ushort_t*)(ws + 286720);  // 4 planes [256][256] bf16
  ushort_t* Gp    = (ushort_t*)(ws + 417792);  // 4 planes [256][256] bf16
  float*  R1    = ws + 548864;               // region1: 8 MB (2,097,152 fl)
  float*  R2    = ws + 2646016;              // region2: 8 MB

  // region1 tenants (sequential lifetimes): A planes -> X planes -> AT planes -> Wt planes
  ushort_t* Aplanes = (ushort_t*)R1;  // 4 x [256][4096]
  ushort_t* Xplanes = (ushort_t*)R1;  // 4 x [256][2048]
  ushort_t* ATp     = (ushort_t*)R1;  // 4 x [4096][256]
  ushort_t* Wtp     = (ushort_t*)R1;  // 4 x [4096][256]
  // region2 tenants: Newton (Xa,Xb,Tt) -> W
  float2* Xa = (float2*)R2;
  float2* Xb = Xa + 65536;
  float2* Tt = Xb + 65536;
  float2* W  = (float2*)R2;           // overwrites Xa/Xb/Tt after Newton done
  float2* Rc = (float2*)Rf;
  float2* Gc = (float2*)Gf;

  // 1) init R (ridge diag), G, q, d
  k_zero<<<1056, 256, 0, stream>>>(ws);
  // 2) A -> split-bf16 planes (sqrt(gamma) folded), gram -> R
  k_conv<<<(MM * LL) / 256, 256, 0, stream>>>(Are, Aim, gamma, LL - 1, Aplanes, MM * LL);
  k_gram_mfma<<<dim3(16, 16), 256, 0, stream>>>(Aplanes, MM * LL, LL, LL / 16, Rf);
  // 3) X -> planes (region1 reuse), gram -> G
  k_conv<<<(MM * TT) / 256, 256, 0, stream>>>(Xre, Xim, nullptr, TT - 1, Xplanes, MM * TT);
  k_gram_mfma<<<dim3(16, 8), 256, 0, stream>>>(Xplanes, MM * TT, TT, TT / 8, Gf);
  // 4) G -> planes; A^T -> planes (region1 reuse)
  k_conv256<<<256, 256, 0, stream>>>(Gc, Gp);
  k_transpA<<<dim3(128, 8), 256, 0, stream>>>(Are, Aim, ATp);
  // 5) Newton-Schulz inverse (fp32), 6 iterations
  k_x0<<<256, 256, 0, stream>>>(Rc, Xa);
  float2* cur = Xa;
  float2* oth = Xb;
  for (int it = 0; it < 6; ++it) {
    k_zgemm256<<<256, 256, 0, stream>>>(Rc, cur, Tt, 0);
    k_zgemm256<<<256, 256, 0, stream>>>(cur, Tt, oth, 1);
    float2* t = cur; cur = oth; oth = t;
  }
  // 6) Rinv -> planes; W = Rinv @ A (writes W + d atomics)
  k_conv256<<<256, 256, 0, stream>>>(cur, Rinvp);
  k_wide_mfma<<<dim3(64, 4), 256, 0, stream>>>(Rinvp, ATp, Are, Aim, nullptr, W, dv_, 0);
  // 7) W^T -> planes (region1 reuse); Y = G @ W folded into q atomics
  k_transpW<<<dim3(128, 8), 256, 0, stream>>>(W, Wtp);
  k_wide_mfma<<<dim3(64, 4), 256, 0, stream>>>(Gp, Wtp, nullptr, nullptr, W, nullptr, qv_, 1);
  // 8) epilogue chain
  k_uv<<<16, 256, 0, stream>>>(qv_, dv_, gamma, delta, vvec, uvec);
  k_ln<<<1, 256, 0, stream>>>(uvec, lnw, lnb, upv);
  k_gate<<<LL, 256, 0, stream>>>(gateW, uvec, gateb, gv);
  k_attn<<<LL, 256, 0, stream>>>(upv, inw, inb, outw, outb, gv, vvec, gamma, lmbda, out);
}